// Round 1
// baseline (236.555 us; speedup 1.0000x reference)
//
#include <hip/hip_runtime.h>

#define K  100   // NUM_BREAKPOINTS
#define NB 1024  // LUT buckets (power of 2 -> exact fp bucket math)

typedef float fvec4 __attribute__((ext_vector_type(4)));

// ---------------------------------------------------------------------------
// Setup kernel (1 block, 1024 threads, ~µs): sort breakpoints, compute betas,
// fold each segment to y = a*x + b, and build a 1024-bucket search LUT.
// ws layout: [0,4096)   u32 lut[NB]      packed (lo | hi<<16)
//            [4096,4496) f32 sx[K]       sorted breakpoints
//            [4608,5408) float2 ab[K]    (a, b) per segment
// ---------------------------------------------------------------------------
__global__ __launch_bounds__(1024) void pwl_setup_kernel(
    const float* __restrict__ xp, const float* __restrict__ sl,
    const float* __restrict__ bias, unsigned int* __restrict__ lut_g,
    float* __restrict__ sx_g, float2* __restrict__ ab_g) {
  __shared__ float s_pos[K];
  __shared__ float s_slope[K];
  __shared__ float s_sorted[K];
  __shared__ float s_beta[K];
  __shared__ unsigned short s_cnt[NB + 1];
  const int t = threadIdx.x;

  if (t < K) { s_pos[t] = xp[t]; s_slope[t] = sl[t]; }
  __syncthreads();

  // O(K^2) stable rank sort (ties broken by original index)
  if (t < K) {
    float v = s_pos[t];
    int r = 0;
    for (int j = 0; j < K; ++j) {
      float u = s_pos[j];
      r += ((u < v) || (u == v && j < t)) ? 1 : 0;
    }
    s_sorted[r] = v;
  }
  __syncthreads();

  // beta[i] = bias + sum_{j<i} (sorted[j+1]-sorted[j]) * slope[j]
  if (t == 0) {
    float acc = bias[0];
    s_beta[0] = acc;
    for (int i = 1; i < K; ++i) {
      acc = acc + (s_sorted[i] - s_sorted[i - 1]) * s_slope[i - 1];
      s_beta[i] = acc;
    }
  }
  __syncthreads();

  if (t < K) {
    float a = s_slope[t];
    float b = s_beta[t] - s_sorted[t] * a;  // y = a*x + b on segment t
    sx_g[t] = s_sorted[t];
    ab_g[t] = make_float2(a, b);
  }

  // cnt at each bucket edge e/NB: number of sorted breakpoints <= edge
  for (int e = t; e <= NB; e += blockDim.x) {
    float ev = (float)e * (1.0f / (float)NB);  // exact (pow2 scale)
    int c = 0;
    for (int j = 0; j < K; ++j) c += (s_sorted[j] <= ev) ? 1 : 0;
    s_cnt[e] = (unsigned short)c;
  }
  __syncthreads();

  for (int b = t; b < NB; b += blockDim.x) {
    lut_g[b] = (unsigned int)s_cnt[b] | ((unsigned int)s_cnt[b + 1] << 16);
  }
}

// ---------------------------------------------------------------------------
// Main streaming kernel: memory-bound, float4 nontemporal in/out.
// ---------------------------------------------------------------------------
__device__ __forceinline__ float pwl_eval(float xv,
                                          const unsigned int* __restrict__ s_lut,
                                          const float* __restrict__ s_x,
                                          const float2* __restrict__ s_ab) {
  int b = (int)(xv * (float)NB);          // exact pow2 scale; trunc toward 0
  b = min(max(b, 0), NB - 1);
  unsigned int p = s_lut[b];
  int lo = (int)(p & 0xffffu);
  int hi = (int)(p >> 16);
  // upper_bound within [lo,hi); ~90% of buckets have lo==hi already
  while (lo < hi) {
    int mid = (lo + hi) >> 1;
    if (s_x[mid] <= xv) lo = mid + 1; else hi = mid;
  }
  int idx = min(max(lo, 1), K) - 1;       // clip(cnt,1,K)-1
  float2 ab = s_ab[idx];
  float y = fmaf(xv, ab.x, ab.y);
  return fminf(fmaxf(y, 0.0f), 1.0f);
}

__global__ __launch_bounds__(256) void pwl_main_kernel(
    const fvec4* __restrict__ x, const unsigned int* __restrict__ lut_g,
    const float* __restrict__ sx_g, const float2* __restrict__ ab_g,
    fvec4* __restrict__ out, int n4, int n) {
  __shared__ unsigned int s_lut[NB];
  __shared__ float s_x[K];
  __shared__ float2 s_ab[K];
  for (int i = threadIdx.x; i < NB; i += blockDim.x) s_lut[i] = lut_g[i];
  if (threadIdx.x < K) {
    s_x[threadIdx.x] = sx_g[threadIdx.x];
    s_ab[threadIdx.x] = ab_g[threadIdx.x];
  }
  __syncthreads();

  const int stride = gridDim.x * blockDim.x;
  for (int i = blockIdx.x * blockDim.x + threadIdx.x; i < n4; i += stride) {
    fvec4 v = __builtin_nontemporal_load(&x[i]);
    fvec4 r;
    r.x = pwl_eval(v.x, s_lut, s_x, s_ab);
    r.y = pwl_eval(v.y, s_lut, s_x, s_ab);
    r.z = pwl_eval(v.z, s_lut, s_x, s_ab);
    r.w = pwl_eval(v.w, s_lut, s_x, s_ab);
    __builtin_nontemporal_store(r, &out[i]);
  }

  // scalar tail (n % 4), handled by block 0
  if (blockIdx.x == 0) {
    const float* xs = (const float*)x;
    float* os = (float*)out;
    for (int i = (n4 << 2) + threadIdx.x; i < n; i += blockDim.x) {
      os[i] = pwl_eval(xs[i], s_lut, s_x, s_ab);
    }
  }
}

extern "C" void kernel_launch(void* const* d_in, const int* in_sizes, int n_in,
                              void* d_out, int out_size, void* d_ws, size_t ws_size,
                              hipStream_t stream) {
  const float* x    = (const float*)d_in[0];
  const float* xp   = (const float*)d_in[1];
  const float* sl   = (const float*)d_in[2];
  const float* bias = (const float*)d_in[3];
  float* out = (float*)d_out;

  unsigned int* lut = (unsigned int*)d_ws;                      // 4096 B
  float* sx         = (float*)((char*)d_ws + NB * 4);           // 400 B (+pad)
  float2* ab        = (float2*)((char*)d_ws + NB * 4 + 512);    // 800 B, 8B-aligned

  const int n  = in_sizes[0];
  const int n4 = n >> 2;

  pwl_setup_kernel<<<1, 1024, 0, stream>>>(xp, sl, bias, lut, sx, ab);

  const int threads = 256;
  const int blocks  = 2048;  // 8 blocks/CU * 4 waves = full 32 waves/CU
  pwl_main_kernel<<<blocks, threads, 0, stream>>>(
      (const fvec4*)x, lut, sx, ab, (fvec4*)out, n4, n);
}

// Round 2
// 236.513 us; speedup vs baseline: 1.0002x; 1.0002x over previous
//
#include <hip/hip_runtime.h>

#define K  100   // NUM_BREAKPOINTS
#define NB 1024  // LUT buckets (power of 2 -> exact fp bucket math)

typedef float fvec4 __attribute__((ext_vector_type(4)));

// ---------------------------------------------------------------------------
// Setup kernel (1 block): sort breakpoints, fold each segment to y = a*x + b,
// and build a 1024-bucket DIRECT table: clean buckets (no interior breakpoint)
// hold (a,b) inline; dirty buckets hold (+inf, packed lo|hi<<16) for fallback.
// ws layout: [0,8192)      float2 bab[NB]
//            [8192,8592)   f32 sx[K]
//            [8704,9504)   float2 ab[K]
// ---------------------------------------------------------------------------
__global__ __launch_bounds__(1024) void pwl_setup_kernel(
    const float* __restrict__ xp, const float* __restrict__ sl,
    const float* __restrict__ bias, float2* __restrict__ bab_g,
    float* __restrict__ sx_g, float2* __restrict__ ab_g) {
  __shared__ float s_pos[K];
  __shared__ float s_slope[K];
  __shared__ float s_sorted[K];
  __shared__ float s_a[K];
  __shared__ float s_b[K];
  __shared__ unsigned short s_cnt[NB + 1];
  const int t = threadIdx.x;

  if (t < K) { s_pos[t] = xp[t]; s_slope[t] = sl[t]; }
  __syncthreads();

  // O(K^2) stable rank sort (ties broken by original index)
  if (t < K) {
    float v = s_pos[t];
    int r = 0;
    for (int j = 0; j < K; ++j) {
      float u = s_pos[j];
      r += ((u < v) || (u == v && j < t)) ? 1 : 0;
    }
    s_sorted[r] = v;
  }
  __syncthreads();

  // beta[i] = bias + sum_{j<i} (sorted[j+1]-sorted[j]) * slope[j]; fold to a,b
  if (t == 0) {
    float acc = bias[0];
    for (int i = 0; i < K; ++i) {
      if (i) acc += (s_sorted[i] - s_sorted[i - 1]) * s_slope[i - 1];
      float a = s_slope[i];
      s_a[i] = a;
      s_b[i] = acc - s_sorted[i] * a;  // y = a*x + b on segment i
    }
  }
  __syncthreads();

  if (t < K) {
    sx_g[t] = s_sorted[t];
    ab_g[t] = make_float2(s_a[t], s_b[t]);
  }

  // cnt at each bucket edge e/NB: number of sorted breakpoints <= edge (exact)
  for (int e = t; e <= NB; e += blockDim.x) {
    float ev = (float)e * (1.0f / (float)NB);  // exact (pow2 scale)
    int c = 0;
    for (int j = 0; j < K; ++j) c += (s_sorted[j] <= ev) ? 1 : 0;
    s_cnt[e] = (unsigned short)c;
  }
  __syncthreads();

  // direct bucket table
  for (int b = t; b < NB; b += blockDim.x) {
    int lo = s_cnt[b], hi = s_cnt[b + 1];
    float2 e;
    if (lo == hi) {                      // clean: segment fully determined
      int idx = min(max(lo, 1), K) - 1;  // clip(cnt,1,K)-1
      e = make_float2(s_a[idx], s_b[idx]);
    } else {                             // dirty: marker + packed search range
      e.x = __builtin_huge_valf();
      e.y = __uint_as_float((unsigned)lo | ((unsigned)hi << 16));
    }
    bab_g[b] = e;
  }
}

// ---------------------------------------------------------------------------
// Main streaming kernel: memory-bound, float4 nontemporal in/out, one random
// ds_read_b64 per element on the common path.
// ---------------------------------------------------------------------------
__device__ __forceinline__ float pwl_eval(float xv,
                                          const float2* __restrict__ s_bab,
                                          const float* __restrict__ s_x,
                                          const float2* __restrict__ s_ab) {
  int b = (int)(xv * (float)NB);  // exact pow2 scale; trunc toward 0
  b = min(max(b, 0), NB - 1);
  float2 ab = s_bab[b];
  if (__float_as_uint(ab.x) == 0x7f800000u) {  // dirty bucket (~9%)
    unsigned p = __float_as_uint(ab.y);
    int lo = (int)(p & 0xffffu);
    int hi = (int)(p >> 16);
    while (lo < hi) {  // upper_bound; dirty buckets usually have hi-lo==1
      int mid = (lo + hi) >> 1;
      if (s_x[mid] <= xv) lo = mid + 1; else hi = mid;
    }
    int idx = min(max(lo, 1), K) - 1;
    ab = s_ab[idx];
  }
  float y = fmaf(xv, ab.x, ab.y);
  return fminf(fmaxf(y, 0.0f), 1.0f);
}

__global__ __launch_bounds__(256) void pwl_main_kernel(
    const fvec4* __restrict__ x, const float2* __restrict__ bab_g,
    const float* __restrict__ sx_g, const float2* __restrict__ ab_g,
    fvec4* __restrict__ out, int n4, int n) {
  __shared__ float2 s_bab[NB];
  __shared__ float s_x[K];
  __shared__ float2 s_ab[K];
  for (int i = threadIdx.x; i < NB; i += blockDim.x) s_bab[i] = bab_g[i];
  if (threadIdx.x < K) {
    s_x[threadIdx.x] = sx_g[threadIdx.x];
    s_ab[threadIdx.x] = ab_g[threadIdx.x];
  }
  __syncthreads();

  const int stride = gridDim.x * blockDim.x;
  int i = blockIdx.x * blockDim.x + threadIdx.x;
  if (i < n4) {
    // software-pipelined: next load in flight while processing current
    fvec4 v = __builtin_nontemporal_load(&x[i]);
    while (true) {
      int inext = i + stride;
      bool more = inext < n4;
      fvec4 vn = {};
      if (more) vn = __builtin_nontemporal_load(&x[inext]);
      fvec4 r;
      r.x = pwl_eval(v.x, s_bab, s_x, s_ab);
      r.y = pwl_eval(v.y, s_bab, s_x, s_ab);
      r.z = pwl_eval(v.z, s_bab, s_x, s_ab);
      r.w = pwl_eval(v.w, s_bab, s_x, s_ab);
      __builtin_nontemporal_store(r, &out[i]);
      if (!more) break;
      v = vn;
      i = inext;
    }
  }

  // scalar tail (n % 4), handled by block 0 (empty for this shape)
  if (blockIdx.x == 0) {
    const float* xs = (const float*)x;
    float* os = (float*)out;
    for (int j = (n4 << 2) + threadIdx.x; j < n; j += blockDim.x) {
      os[j] = pwl_eval(xs[j], s_bab, s_x, s_ab);
    }
  }
}

extern "C" void kernel_launch(void* const* d_in, const int* in_sizes, int n_in,
                              void* d_out, int out_size, void* d_ws, size_t ws_size,
                              hipStream_t stream) {
  const float* x    = (const float*)d_in[0];
  const float* xp   = (const float*)d_in[1];
  const float* sl   = (const float*)d_in[2];
  const float* bias = (const float*)d_in[3];
  float* out = (float*)d_out;

  float2* bab = (float2*)d_ws;                               // 8192 B
  float* sx   = (float*)((char*)d_ws + NB * 8);              // 400 B (+pad)
  float2* ab  = (float2*)((char*)d_ws + NB * 8 + 512);       // 800 B, 8B-aligned

  const int n  = in_sizes[0];
  const int n4 = n >> 2;

  pwl_setup_kernel<<<1, 1024, 0, stream>>>(xp, sl, bias, bab, sx, ab);

  const int threads = 256;
  const int blocks  = 2048;  // 8 blocks/CU * 4 waves = full 32 waves/CU
  pwl_main_kernel<<<blocks, threads, 0, stream>>>(
      (const fvec4*)x, bab, sx, ab, (fvec4*)out, n4, n);
}